// Round 1
// baseline (151126.624 us; speedup 1.0000x reference)
//
#include <hip/hip_runtime.h>
#include <hip/hip_bf16.h>
#include <cstdint>

// LSTM, T=32768 steps, C=512, I=1024 (x 512 | h 512), fp32.
// Strategy:
//   1) gx[t][*] = Wx @ x_t + b  -- parallel GEMM over all timesteps (chunked in ws)
//   2) serial recurrence: 32 persistent-ish blocks, each owns 16 (c,h) outputs
//      and holds its 64 gate rows (4 gates x 16) of Wh in VGPRs (128 f32/thread).
//      Per step only h (512 f32) crosses blocks, via device-scope counter sync.

#define T_TOTAL 32768
#define NBLK 32

__device__ __forceinline__ float sigm(float x) {
    return 1.0f / (1.0f + __expf(-x));
}
__device__ __forceinline__ float tanh_fast(float x) {
    float ax = fabsf(x);
    float e = __expf(2.0f * ax);          // +inf for large ax is fine -> t = 1
    float t = 1.0f - 2.0f / (e + 1.0f);
    return copysignf(t, x);
}

// ---------------------------------------------------------------------------
// GEMM: gx[(t-t0)*2048 + ((jg>>4)*4 + g)*16 + (jg&15)] = b[j] + sum_k W[j][0:512]·x[t]
// Layout is block-major for the serial kernel: block b reads 64 contiguous floats.
// grid = (ceil(steps/16), 16 j-tiles of 128), block = 256.
// ---------------------------------------------------------------------------
__global__ __launch_bounds__(256, 1) void lstm_gemm_x(
    const float* __restrict__ x,
    const float* __restrict__ wf, const float* __restrict__ wi,
    const float* __restrict__ wc, const float* __restrict__ wo,
    const float* __restrict__ bf, const float* __restrict__ bi,
    const float* __restrict__ bc, const float* __restrict__ bo,
    float* __restrict__ gx, int t0, int tend)
{
    __shared__ float xs[16][512];
    const int tid = threadIdx.x;
    const int tt0 = t0 + blockIdx.x * 16;
    const int j0  = blockIdx.y * 128;

    // stage x tile [16][512] (32 KB), coalesced float4
    #pragma unroll
    for (int i = 0; i < 8; ++i) {
        int idx  = tid + i * 256;          // 0..2047 float4 chunks
        int trow = idx >> 7, kq = idx & 127;
        int t    = tt0 + trow;
        float4 v = make_float4(0.f, 0.f, 0.f, 0.f);
        if (t < tend) v = *(const float4*)(x + (size_t)t * 512 + kq * 4);
        *(float4*)&xs[trow][kq * 4] = v;
    }
    __syncthreads();

    const int j  = j0 + (tid & 127);       // global fused row 0..2047
    const int th = tid >> 7;               // 0..1 (t-half)
    const int g  = j >> 9;
    const int jg = j & 511;
    const float* Wg = (g == 0) ? wf : (g == 1) ? wi : (g == 2) ? wc : wo;
    const float* Bg = (g == 0) ? bf : (g == 1) ? bi : (g == 2) ? bc : bo;
    const float* wrow = Wg + (size_t)jg * 1024;   // x-part = cols 0..511

    float acc[8];
    #pragma unroll
    for (int i = 0; i < 8; ++i) acc[i] = 0.f;

    for (int k = 0; k < 512; k += 4) {
        float4 w4 = *(const float4*)(wrow + k);    // L2-resident after warmup
        #pragma unroll
        for (int tt = 0; tt < 8; ++tt) {
            float4 x4 = *(const float4*)&xs[th * 8 + tt][k];  // wave-uniform addr: broadcast
            acc[tt] = fmaf(w4.x, x4.x, acc[tt]);
            acc[tt] = fmaf(w4.y, x4.y, acc[tt]);
            acc[tt] = fmaf(w4.z, x4.z, acc[tt]);
            acc[tt] = fmaf(w4.w, x4.w, acc[tt]);
        }
    }

    const float bias = Bg[jg];
    const int   obase = ((jg >> 4) * 4 + g) * 16 + (jg & 15);
    #pragma unroll
    for (int tt = 0; tt < 8; ++tt) {
        int t = tt0 + th * 8 + tt;
        if (t < tend) gx[(size_t)(t - t0) * 2048 + obase] = acc[tt] + bias;
    }
}

// ---------------------------------------------------------------------------
// Serial recurrence. grid = 32 blocks x 256 threads (all co-resident).
// Block b owns c/h indices [b*16, b*16+16). Thread map: tid = r*16 + g*4 + seg
//   r   = tid>>4     (0..15, output row within slice)
//   g   = (tid>>2)&3 (gate: 0=f 1=i 2=c 3=o)
//   seg = tid&3      (k-segment of 128 of the h-dot)
// Weights: 32 float4 in VGPRs, stored XOR-swizzled so the 4 segs of a quad
// read distinct LDS bank groups each unrolled step.
// Sync per step: store h slice -> __threadfence -> atomicAdd(cnt[t]);
// readers spin relaxed on cnt[t-1]==32, then acquire fence, then stage h to LDS.
// h double-buffered (slot = t&1); safe because a block only reaches step t
// after every block finished writing h_{t-1} (hence finished reading h_{t-2}).
// ---------------------------------------------------------------------------
__global__ __launch_bounds__(256, 1) void lstm_serial(
    const float* __restrict__ wf, const float* __restrict__ wi,
    const float* __restrict__ wc, const float* __restrict__ wo,
    const float* __restrict__ gx, float* __restrict__ hbuf,
    float* __restrict__ cstate, unsigned* __restrict__ cnt,
    int t0, int steps, float* __restrict__ out)
{
    __shared__ float hl[512];
    const int b   = blockIdx.x;
    const int tid = threadIdx.x;
    const int r   = tid >> 4;
    const int g   = (tid >> 2) & 3;
    const int seg = tid & 3;

    const float* Wg  = (g == 0) ? wf : (g == 1) ? wi : (g == 2) ? wc : wo;
    const float* wrow = Wg + (size_t)(b * 16 + r) * 1024 + 512 + seg * 128; // h-part
    const float4* wrow4 = (const float4*)wrow;

    float4 w4[32];
    #pragma unroll
    for (int ii = 0; ii < 32; ++ii) w4[ii] = wrow4[ii ^ seg];  // XOR-swizzled order

    float cold = cstate[b * 16 + r];     // all 16 lanes of an r-group hold a copy
    const int lane  = tid & 63;
    const int lbase = lane & 48;         // base lane of this r-group within the wave
    const float4* h4 = (const float4*)hl;

    for (int s = 0; s < steps; ++s) {
        const int t    = t0 + s;
        const int slot = t & 1;

        // prefetch gx early (independent of h sync; 4 segs broadcast-load same addr)
        const float gxv = gx[(size_t)s * 2048 + (b << 6) + (g << 4) + r];

        if (t > 0) {
            if (tid == 0) {
                int guard = 0;
                while (__hip_atomic_load(cnt + (t - 1), __ATOMIC_RELAXED,
                                         __HIP_MEMORY_SCOPE_AGENT) < NBLK &&
                       guard < (1 << 20)) ++guard;
                __threadfence();   // acquire: invalidate stale cached h lines
            }
        }
        __syncthreads();

        // stage h_{t-1} into LDS (2 KB)
        if (tid < 128) {
            float4 hv = *(const float4*)(hbuf + ((slot ^ 1) << 9) + tid * 4);
            *(float4*)&hl[tid * 4] = hv;
        }
        __syncthreads();

        // 128-wide dot: w4[ii] pairs h-chunk (ii^seg); 4 independent FMA chains
        float4 av = make_float4(0.f, 0.f, 0.f, 0.f);
        #pragma unroll
        for (int ii = 0; ii < 32; ++ii) {
            float4 hv = h4[(seg << 5) + (ii ^ seg)];
            av.x = fmaf(w4[ii].x, hv.x, av.x);
            av.y = fmaf(w4[ii].y, hv.y, av.y);
            av.z = fmaf(w4[ii].z, hv.z, av.z);
            av.w = fmaf(w4[ii].w, hv.w, av.w);
        }
        float acc = (av.x + av.y) + (av.z + av.w);
        acc += (seg == 0) ? gxv : 0.f;

        // reduce the 4 segs of each row-quad
        acc += __shfl_xor(acc, 1);
        acc += __shfl_xor(acc, 2);

        // gather the 4 gate values of this r from within the wave
        float gf = __shfl(acc, lbase);
        float gi = __shfl(acc, lbase + 4);
        float gc = __shfl(acc, lbase + 8);
        float go = __shfl(acc, lbase + 12);

        float ff  = sigm(gf);
        float iiv = sigm(gi);
        float ccv = tanh_fast(gc);
        float ov  = sigm(go);
        cold = fmaf(ff, cold, iiv * ccv);
        float hnew = tanh_fast(cold) * ov;

        if ((tid & 15) == 0) {
            hbuf[(slot << 9) + b * 16 + r] = hnew;
            if (t == T_TOTAL - 1) {
                out[b * 16 + r]       = cold;
                out[512 + b * 16 + r] = hnew;
            }
        }
        __syncthreads();                  // all waves' stores drained (vmcnt before barrier)
        if (tid == 0) {
            __threadfence();              // release: flush h slice to coherent point
            __hip_atomic_fetch_add(cnt + t, 1u, __ATOMIC_RELAXED,
                                   __HIP_MEMORY_SCOPE_AGENT);
        }
    }

    if ((tid & 15) == 0) cstate[b * 16 + r] = cold;
}

// ---------------------------------------------------------------------------
extern "C" void kernel_launch(void* const* d_in, const int* in_sizes, int n_in,
                              void* d_out, int out_size, void* d_ws, size_t ws_size,
                              hipStream_t stream)
{
    const float* x  = (const float*)d_in[0];
    const float* wf = (const float*)d_in[1];
    const float* bf = (const float*)d_in[2];
    const float* wi = (const float*)d_in[3];
    const float* bi = (const float*)d_in[4];
    const float* wc = (const float*)d_in[5];
    const float* bc = (const float*)d_in[6];
    const float* wo = (const float*)d_in[7];
    const float* bo = (const float*)d_in[8];
    float* out = (float*)d_out;

    char* wsb = (char*)d_ws;
    unsigned* cnt = (unsigned*)wsb;                          // 32768*4 = 131072 B
    float* hbuf   = (float*)(wsb + 131072);                  // 2*512*4 = 4096 B
    float* cst    = (float*)(wsb + 131072 + 4096);           // 512*4   = 2048 B
    const size_t metaBytes = 131072 + 4096 + 2048;           // 137216 (16B aligned)
    float* gxbuf  = (float*)(wsb + metaBytes);

    // adaptive chunking of the gx buffer into remaining workspace
    size_t gxCapSteps = (ws_size > metaBytes)
                        ? (ws_size - metaBytes) / (2048 * sizeof(float)) : 0;
    int CH = (gxCapSteps < (size_t)T_TOTAL) ? (int)gxCapSteps : T_TOTAL;
    CH &= ~15;
    if (CH < 16) CH = 16;

    hipMemsetAsync(wsb, 0, metaBytes, stream);   // zero counters + h ring + c state

    for (int t0 = 0; t0 < T_TOTAL; t0 += CH) {
        int tend  = t0 + CH; if (tend > T_TOTAL) tend = T_TOTAL;
        int steps = tend - t0;
        dim3 ggrid((steps + 15) / 16, 16);
        lstm_gemm_x<<<ggrid, 256, 0, stream>>>(x, wf, wi, wc, wo,
                                               bf, bi, bc, bo, gxbuf, t0, tend);
        lstm_serial<<<NBLK, 256, 0, stream>>>(wf, wi, wc, wo, gxbuf,
                                              hbuf, cst, cnt, t0, steps, out);
    }
}

// Round 4
// 89903.033 us; speedup vs baseline: 1.6810x; 1.6810x over previous
//
#include <hip/hip_runtime.h>
#include <hip/hip_bf16.h>
#include <cstdint>

// LSTM, T=32768 steps, C=512, I=1024 (x 512 | h 512), fp32.
//   1) gx[t][*] = Wx @ x_t + b  -- parallel GEMM over all timesteps (chunked in ws)
//   2) serial recurrence: 32 blocks x 256 threads, each block owns 16 (c,h) rows;
//      Wh rows pinned in VGPRs (32 named float4 = 128 regs, asm keep-alive).
//      Per-step sync: fence-free all-RMW mailbox (atomicExch data + flag at the
//      device coherence point; relaxed agent atomic loads on the read side).
//      R1 proved this primitive class coherent (RMW visible to relaxed polls).

#define T_TOTAL 32768
#define NBLK 32

__device__ __forceinline__ float sigm(float x) {
    return 1.0f / (1.0f + __expf(-x));
}
__device__ __forceinline__ float tanh_fast(float x) {
    float ax = fabsf(x);
    float e = __expf(2.0f * ax);          // +inf for large ax is fine -> t = 1
    float t = 1.0f - 2.0f / (e + 1.0f);
    return copysignf(t, x);
}

// ---------------------------------------------------------------------------
// GEMM: gx[(t-t0)*2048 + ((jg>>4)*4 + g)*16 + (jg&15)] = b[j] + W[j][0:512]·x[t]
// Layout is block-major for the serial kernel: block b reads 64 contiguous floats.
// ---------------------------------------------------------------------------
__global__ __launch_bounds__(256, 1) void lstm_gemm_x(
    const float* __restrict__ x,
    const float* __restrict__ wf, const float* __restrict__ wi,
    const float* __restrict__ wc, const float* __restrict__ wo,
    const float* __restrict__ bf, const float* __restrict__ bi,
    const float* __restrict__ bc, const float* __restrict__ bo,
    float* __restrict__ gx, int t0, int tend)
{
    __shared__ float xs[16][512];
    const int tid = threadIdx.x;
    const int tt0 = t0 + blockIdx.x * 16;
    const int j0  = blockIdx.y * 128;

    #pragma unroll
    for (int i = 0; i < 8; ++i) {
        int idx  = tid + i * 256;
        int trow = idx >> 7, kq = idx & 127;
        int t    = tt0 + trow;
        float4 v = make_float4(0.f, 0.f, 0.f, 0.f);
        if (t < tend) v = *(const float4*)(x + (size_t)t * 512 + kq * 4);
        *(float4*)&xs[trow][kq * 4] = v;
    }
    __syncthreads();

    const int j  = j0 + (tid & 127);
    const int th = tid >> 7;
    const int g  = j >> 9;
    const int jg = j & 511;
    const float* Wg = (g == 0) ? wf : (g == 1) ? wi : (g == 2) ? wc : wo;
    const float* Bg = (g == 0) ? bf : (g == 1) ? bi : (g == 2) ? bc : bo;
    const float* wrow = Wg + (size_t)jg * 1024;

    float acc[8];
    #pragma unroll
    for (int i = 0; i < 8; ++i) acc[i] = 0.f;

    for (int k = 0; k < 512; k += 4) {
        float4 w4 = *(const float4*)(wrow + k);
        #pragma unroll
        for (int tt = 0; tt < 8; ++tt) {
            float4 x4 = *(const float4*)&xs[th * 8 + tt][k];
            acc[tt] = fmaf(w4.x, x4.x, acc[tt]);
            acc[tt] = fmaf(w4.y, x4.y, acc[tt]);
            acc[tt] = fmaf(w4.z, x4.z, acc[tt]);
            acc[tt] = fmaf(w4.w, x4.w, acc[tt]);
        }
    }

    const float bias = Bg[jg];
    const int   obase = ((jg >> 4) * 4 + g) * 16 + (jg & 15);
    #pragma unroll
    for (int tt = 0; tt < 8; ++tt) {
        int t = tt0 + th * 8 + tt;
        if (t < tend) gx[(size_t)(t - t0) * 2048 + obase] = acc[tt] + bias;
    }
}

// ---------------------------------------------------------------------------
// Serial recurrence. grid = 32 blocks x 256 threads (all co-resident: 32<=256 CUs).
// Thread map: tid = r*16 + g*4 + seg (r=row-in-slice, g=gate, seg=k-quarter).
// Mailbox per step t (slot sc=t&1 receives h_t; sp=sc^1 holds h_{t-1}):
//   publish: r-owner threads (tid&15==0) atomicExch h_t words into hbuf[sc];
//     __syncthreads (per-wave vmcnt(0) drains the RMWs); tid0 atomicExch
//     flag[sc][b]=t+1. MALL order: flag arrives after data acks.
//   consume: thread tid relaxed-polls flag[sp][tid>>3] >= t, then relaxed
//     atomic-loads its u64 of hbuf[sp], stages to LDS.
// Slot reuse safe: a block publishes h_{t+1} only after observing all flags
// for h_t, which happen-after every block consumed h_{t-1}.
// ---------------------------------------------------------------------------
__global__ __launch_bounds__(256, 1) void lstm_serial(
    const float* __restrict__ wf, const float* __restrict__ wi,
    const float* __restrict__ wc, const float* __restrict__ wo,
    const float* __restrict__ gx,
    unsigned* __restrict__ hbuf,            // [2][512] u32 h mailbox
    unsigned* __restrict__ hflag,           // [2][32][16] (64B-padded flags)
    float* __restrict__ cstate,
    int t0, int steps, float* __restrict__ out)
{
    __shared__ alignas(16) float hl[512];
    const int b   = blockIdx.x;
    const int tid = threadIdx.x;
    const int r   = tid >> 4;
    const int g   = (tid >> 2) & 3;
    const int seg = tid & 3;
    const int sb  = tid >> 3;              // source block whose flag this thread polls

    const float* Wg = (g == 0) ? wf : (g == 1) ? wi : (g == 2) ? wc : wo;
    // h-part of this row, THIS seg's 128-float k-segment (seg*32 float4s).
    const float4* wrow4 = (const float4*)(Wg + (size_t)(b * 16 + r) * 1024 + 512)
                          + seg * 32;

    // --- pin 128 weight floats in VGPRs; asm keep-alive defeats remat-as-load ---
#define WL(i) float4 w##i = wrow4[(i) ^ seg]; \
    asm("" : "+v"(w##i.x), "+v"(w##i.y), "+v"(w##i.z), "+v"(w##i.w));
    WL(0)  WL(1)  WL(2)  WL(3)  WL(4)  WL(5)  WL(6)  WL(7)
    WL(8)  WL(9)  WL(10) WL(11) WL(12) WL(13) WL(14) WL(15)
    WL(16) WL(17) WL(18) WL(19) WL(20) WL(21) WL(22) WL(23)
    WL(24) WL(25) WL(26) WL(27) WL(28) WL(29) WL(30) WL(31)
#undef WL

    float cold = cstate[b * 16 + r];
    const int lane  = tid & 63;
    const int lbase = lane & 48;
    const float4* h4 = (const float4*)hl;
    const int hbase = seg << 5;

    for (int s = 0; s < steps; ++s) {
        const int t  = t0 + s;
        const int sp = (t & 1) ^ 1;        // slot holding h_{t-1}
        const int sc = t & 1;              // slot receiving h_t

        // gx prefetch (independent of sync; in flight during poll)
        const float gxv = gx[(size_t)s * 2048 + (b << 6) + (g << 4) + r];

        {   // poll my source block's flag for h_{t-1} (relaxed observes RMWs)
            const unsigned need = (unsigned)t;
            int guard = 0;
            while (__hip_atomic_load(hflag + (sp * 32 + sb) * 16, __ATOMIC_RELAXED,
                                     __HIP_MEMORY_SCOPE_AGENT) < need &&
                   guard < (1 << 20)) ++guard;
        }
        asm volatile("" ::: "memory");     // no hoisting of the data load above poll
        unsigned long long d = __hip_atomic_load(
            (const unsigned long long*)hbuf + sp * 256 + tid,
            __ATOMIC_RELAXED, __HIP_MEMORY_SCOPE_AGENT);
        ((unsigned long long*)hl)[tid] = d;
        __syncthreads();

        // 128-wide h-dot; XOR-swizzled pairing keeps LDS reads conflict-free
        float4 av = make_float4(0.f, 0.f, 0.f, 0.f);
#define FS(i) { float4 hv = h4[hbase + ((i) ^ seg)];            \
        av.x = fmaf(w##i.x, hv.x, av.x);                        \
        av.y = fmaf(w##i.y, hv.y, av.y);                        \
        av.z = fmaf(w##i.z, hv.z, av.z);                        \
        av.w = fmaf(w##i.w, hv.w, av.w); }
        FS(0)  FS(1)  FS(2)  FS(3)  FS(4)  FS(5)  FS(6)  FS(7)
        FS(8)  FS(9)  FS(10) FS(11) FS(12) FS(13) FS(14) FS(15)
        FS(16) FS(17) FS(18) FS(19) FS(20) FS(21) FS(22) FS(23)
        FS(24) FS(25) FS(26) FS(27) FS(28) FS(29) FS(30) FS(31)
#undef FS
        float acc = (av.x + av.y) + (av.z + av.w);
        acc += (seg == 0) ? gxv : 0.f;

        acc += __shfl_xor(acc, 1);
        acc += __shfl_xor(acc, 2);

        float gf = __shfl(acc, lbase);
        float gi = __shfl(acc, lbase + 4);
        float gc = __shfl(acc, lbase + 8);
        float go = __shfl(acc, lbase + 12);

        float ff  = sigm(gf);
        float iiv = sigm(gi);
        float ccv = tanh_fast(gc);
        float ov  = sigm(go);
        cold = fmaf(ff, cold, iiv * ccv);
        float hnew = tanh_fast(cold) * ov;

        if ((tid & 15) == 0) {             // r-owner publishes its h word (RMW)
            atomicExch(hbuf + sc * 512 + b * 16 + r, __float_as_uint(hnew));
            if (t == T_TOTAL - 1) {
                out[b * 16 + r]       = cold;
                out[512 + b * 16 + r] = hnew;
            }
        }
        __syncthreads();                   // per-wave vmcnt(0): data RMWs performed
        if (tid == 0)
            atomicExch(hflag + (sc * 32 + b) * 16, (unsigned)(t + 1));
    }

    if ((tid & 15) == 0) cstate[b * 16 + r] = cold;
}

// ---------------------------------------------------------------------------
extern "C" void kernel_launch(void* const* d_in, const int* in_sizes, int n_in,
                              void* d_out, int out_size, void* d_ws, size_t ws_size,
                              hipStream_t stream)
{
    const float* x  = (const float*)d_in[0];
    const float* wf = (const float*)d_in[1];
    const float* bf = (const float*)d_in[2];
    const float* wi = (const float*)d_in[3];
    const float* bi = (const float*)d_in[4];
    const float* wc = (const float*)d_in[5];
    const float* bc = (const float*)d_in[6];
    const float* wo = (const float*)d_in[7];
    const float* bo = (const float*)d_in[8];
    float* out = (float*)d_out;

    char* wsb = (char*)d_ws;
    unsigned* hbuf  = (unsigned*)wsb;                        // 2*512*4      = 4096 B
    unsigned* hflag = (unsigned*)(wsb + 4096);               // 2*32*16*4    = 4096 B
    float* cst      = (float*)(wsb + 8192);                  // 512*4        = 2048 B
    const size_t metaBytes = 4096 + 4096 + 2048;             // 10240 (16B aligned)
    float* gxbuf    = (float*)(wsb + metaBytes);

    size_t gxCapSteps = (ws_size > metaBytes)
                        ? (ws_size - metaBytes) / (2048 * sizeof(float)) : 0;
    int CH = (gxCapSteps < (size_t)T_TOTAL) ? (int)gxCapSteps : T_TOTAL;
    CH &= ~15;
    if (CH < 16) CH = 16;

    hipMemsetAsync(wsb, 0, metaBytes, stream);   // zero mailbox + flags + c state

    for (int t0 = 0; t0 < T_TOTAL; t0 += CH) {
        int tend  = t0 + CH; if (tend > T_TOTAL) tend = T_TOTAL;
        int steps = tend - t0;
        dim3 ggrid((steps + 15) / 16, 16);
        lstm_gemm_x<<<ggrid, 256, 0, stream>>>(x, wf, wi, wc, wo,
                                               bf, bi, bc, bo, gxbuf, t0, tend);
        lstm_serial<<<NBLK, 256, 0, stream>>>(wf, wi, wc, wo, gxbuf,
                                              hbuf, hflag, cst, t0, steps, out);
    }
}